// Round 1
// baseline (801.302 us; speedup 1.0000x reference)
//
#include <hip/hip_runtime.h>
#include <hip/hip_bf16.h>

// ---------------------------------------------------------------------------
// IPNN: probs[b,y] = sum_j clip(max(numy[y,j],eps)/max(num[j],eps),0,1) * flat[b,j]
// flat[b,j] = prod_k softmax(logits[b, 16k:16k+16])[s_k],  j = (((s0*16)+s1)*16+s2)*16+s3
// B=1024, Y=100 (padded 128 internally), J=65536
// ---------------------------------------------------------------------------

#define EPS 1e-6f

// ---- Kernel A: per-variable softmax + label extraction --------------------
__global__ __launch_bounds__(128) void kA(const float* __restrict__ logits,
                                          const float* __restrict__ y_true,
                                          float* __restrict__ sm,
                                          int* __restrict__ label) {
    int b = blockIdx.x;
    int t = threadIdx.x;
    if (t < 64) {
        float x = logits[b * 64 + t];
        float m = x;
        for (int mk = 8; mk >= 1; mk >>= 1) m = fmaxf(m, __shfl_xor(m, mk, 16));
        float e = __expf(x - m);
        float s = e;
        for (int mk = 8; mk >= 1; mk >>= 1) s += __shfl_xor(s, mk, 16);
        sm[b * 64 + t] = e / s;
    }
    if (t < 100) {
        if (y_true[b * 100 + t] > 0.5f) label[b] = t;
    }
}

// ---- Kernel B: num_y / num_joint accumulation + py (transposed [j][128]) ---
// grid 256 blocks (256 j each), 256 threads. s0,s1 block-const; s2,s3 thread-const.
// Two passes of 50 y-classes each to keep static LDS under 64 KB.
__global__ __launch_bounds__(256) void kB(const float* __restrict__ sm,
                                          const int* __restrict__ label,
                                          float* __restrict__ py) {
    __shared__ float numy[50 * 257];
    __shared__ float numjl[256];
    __shared__ int lab[1024];
    int t = threadIdx.x;
    int bx = blockIdx.x;
    int jbase = bx << 8;
    int s3 = t & 15, s2 = (t >> 4) & 15;
    int s1 = bx & 15, s0 = (bx >> 4) & 15;

    for (int i = t; i < 1024; i += 256) lab[i] = label[i];

    float numj = 0.f;
    #pragma unroll
    for (int pass = 0; pass < 2; ++pass) {
        for (int i = t; i < 50 * 257; i += 256) numy[i] = 0.f;
        __syncthreads();
        int y0 = pass * 50;
        for (int b = 0; b < 1024; ++b) {
            const float* row = sm + b * 64;
            float f = row[s0] * row[16 + s1] * row[32 + s2] * row[48 + s3];
            if (pass == 0) numj += f;
            unsigned d = (unsigned)(lab[b] - y0);
            if (d < 50u) numy[d * 257 + t] += f;
        }
        if (pass == 0) numjl[t] = numj;
        __syncthreads();
        if (pass == 0) {
            // write y = 0..49
            for (int idx = t; idx < 256 * 50; idx += 256) {
                int j = idx / 50, y = idx % 50;
                float ny = fmaxf(numy[y * 257 + j], EPS);
                float nj = fmaxf(numjl[j], EPS);
                py[(size_t)(jbase + j) * 128 + y] = fminf(ny / nj, 1.0f);
            }
        } else {
            // write y = 50..127 (100..127 padded with zeros)
            for (int idx = t; idx < 256 * 78; idx += 256) {
                int j = idx / 78, y = 50 + idx % 78;
                float v = 0.f;
                if (y < 100) {
                    float ny = fmaxf(numy[(y - 50) * 257 + j], EPS);
                    float nj = fmaxf(numjl[j], EPS);
                    v = fminf(ny / nj, 1.0f);
                }
                py[(size_t)(jbase + j) * 128 + y] = v;
            }
        }
        __syncthreads();
    }
}

// ---- Kernel C: probs partials — fp32 register-tiled GEMM ------------------
// grid (8 b-blocks, jsplit), 256 threads. Block tile 128b x 128y, thread 8x8.
// part[(jblk*128 + y)*1024 + b]
__global__ __launch_bounds__(256) void kC(const float* __restrict__ sm,
                                          const float* __restrict__ py,
                                          float* __restrict__ part,
                                          int jper) {
    __shared__ float smb[128 * 65];  // pitch 65 breaks power-of-2 bank stride
    int t = threadIdx.x;
    int bbase = blockIdx.x << 7;
    int jblk = blockIdx.y;

    for (int i = t; i < 128 * 64; i += 256) {
        smb[(i >> 6) * 65 + (i & 63)] = sm[(size_t)(bbase + (i >> 6)) * 64 + (i & 63)];
    }
    __syncthreads();

    int tb = t & 15, ty = t >> 4;   // b = bbase + tb + 16k (bank-friendly), y = ty*8 + yi
    float acc[8][8];
    #pragma unroll
    for (int k = 0; k < 8; ++k)
        #pragma unroll
        for (int yi = 0; yi < 8; ++yi) acc[k][yi] = 0.f;

    int jstart = jblk * jper;
    int nch = jper >> 4;
    for (int c = 0; c < nch; ++c) {
        int jc = jstart + (c << 4);
        int s0 = (jc >> 12) & 15, s1 = (jc >> 8) & 15, s2 = (jc >> 4) & 15;
        float pre[8];
        #pragma unroll
        for (int k = 0; k < 8; ++k) {
            int bo = (tb + (k << 4)) * 65;
            pre[k] = smb[bo + s0] * smb[bo + 16 + s1] * smb[bo + 32 + s2];
        }
        #pragma unroll 4
        for (int s3 = 0; s3 < 16; ++s3) {
            const float4* pv = reinterpret_cast<const float4*>(py + (size_t)(jc + s3) * 128);
            float4 p0 = pv[ty * 2];
            float4 p1 = pv[ty * 2 + 1];
            float g[8];
            #pragma unroll
            for (int k = 0; k < 8; ++k)
                g[k] = pre[k] * smb[(tb + (k << 4)) * 65 + 48 + s3];
            float pyv[8] = {p0.x, p0.y, p0.z, p0.w, p1.x, p1.y, p1.z, p1.w};
            #pragma unroll
            for (int k = 0; k < 8; ++k)
                #pragma unroll
                for (int yi = 0; yi < 8; ++yi)
                    acc[k][yi] = fmaf(g[k], pyv[yi], acc[k][yi]);
        }
    }

    #pragma unroll
    for (int yi = 0; yi < 8; ++yi) {
        int y = ty * 8 + yi;
        size_t base = ((size_t)jblk * 128 + y) * 1024 + bbase + tb;
        #pragma unroll
        for (int k = 0; k < 8; ++k)
            part[base + (k << 4)] = acc[k][yi];
    }
}

// ---- Kernel D: reduce j-split partials -> out[b*100+y] --------------------
__global__ __launch_bounds__(256) void kD(const float* __restrict__ part,
                                          float* __restrict__ out,
                                          int jsplit) {
    int t = threadIdx.x;
    int y = blockIdx.x >> 2;              // 0..99
    int b = ((blockIdx.x & 3) << 8) + t;  // 0..1023
    float s = 0.f;
    for (int jb = 0; jb < jsplit; ++jb)
        s += part[(((size_t)jb * 128 + y) << 10) + b];
    out[(size_t)b * 100 + y] = s;
}

extern "C" void kernel_launch(void* const* d_in, const int* in_sizes, int n_in,
                              void* d_out, int out_size, void* d_ws, size_t ws_size,
                              hipStream_t stream) {
    const float* logits = (const float*)d_in[0];
    const float* y_true = (const float*)d_in[1];
    float* out = (float*)d_out;

    char* ws = (char*)d_ws;
    float* sm   = (float*)(ws);                    // 262,144 B
    int*   lab  = (int*)(ws + 262144);             // 4,096 B
    float* py   = (float*)(ws + 524288);           // 33,554,432 B
    size_t part_off = 524288 + 33554432ull;
    float* part = (float*)(ws + part_off);

    int jsplit = 64;
    while (jsplit > 1 &&
           part_off + (size_t)jsplit * 128 * 1024 * 4 > ws_size)
        jsplit >>= 1;
    int jper = 65536 / jsplit;

    kA<<<1024, 128, 0, stream>>>(logits, y_true, sm, lab);
    kB<<<256, 256, 0, stream>>>(sm, lab, py);
    dim3 gC(8, jsplit);
    kC<<<gC, 256, 0, stream>>>(sm, py, part, jper);
    kD<<<400, 256, 0, stream>>>(part, out, jsplit);
}

// Round 2
// 394.292 us; speedup vs baseline: 2.0323x; 2.0323x over previous
//
#include <hip/hip_runtime.h>
#include <hip/hip_bf16.h>

// ---------------------------------------------------------------------------
// IPNN: probs[b,y] = sum_j clip(max(numy[y,j],eps)/max(num[j],eps),0,1) * flat[b,j]
// flat[b,j] = prod_k softmax(logits[b,16k:16k+16])[s_k], j = ((s0*16+s1)*16+s2)*16+s3
// B=1024, Y=100 (pad 128), J=65536.  u = s0*16+s1 (outer j), t = s2*16+s3 (inner j)
// ---------------------------------------------------------------------------

#define EPS 1e-6f

// ---- Kernel A: softmax + pair products P01[b,u], P23[b,t] + label ----------
__global__ __launch_bounds__(256) void kA(const float* __restrict__ logits,
                                          const float* __restrict__ y_true,
                                          float* __restrict__ sm,
                                          float* __restrict__ P01,
                                          float* __restrict__ P23,
                                          int* __restrict__ label) {
    __shared__ float row[64];
    int b = blockIdx.x, t = threadIdx.x;
    if (t < 64) {
        float x = logits[b * 64 + t];
        float m = x;
        for (int mk = 8; mk >= 1; mk >>= 1) m = fmaxf(m, __shfl_xor(m, mk, 16));
        float e = __expf(x - m);
        float s = e;
        for (int mk = 8; mk >= 1; mk >>= 1) s += __shfl_xor(s, mk, 16);
        float p = e / s;
        row[t] = p;
        sm[b * 64 + t] = p;
    }
    if (t >= 128 && t < 228) {
        int y = t - 128;
        if (y_true[b * 100 + y] > 0.5f) label[b] = y;
    }
    __syncthreads();
    int hi = t >> 4, lo = t & 15;
    P01[b * 256 + t] = row[hi] * row[16 + lo];
    P23[b * 256 + t] = row[32 + hi] * row[48 + lo];
}

// ---- Kernel S: deterministic counting sort of b by label -------------------
__global__ __launch_bounds__(1024) void kS(const int* __restrict__ label,
                                           int* __restrict__ bidx,
                                           int* __restrict__ ylab) {
    __shared__ int lab[1024];
    __shared__ int offs[101];
    int t = threadIdx.x;
    lab[t] = label[t];
    __syncthreads();
    if (t <= 100) {
        int c = 0;
        for (int b = 0; b < 1024; ++b) c += (lab[b] < t) ? 1 : 0;
        offs[t] = c;
    }
    __syncthreads();
    int my = lab[t];
    int rank = 0;
    for (int b = 0; b < t; ++b) rank += (lab[b] == my) ? 1 : 0;
    int pos = offs[my] + rank;
    bidx[pos] = t;
    ylab[pos] = my;
}

// ---- Kernel B: segmented outer-product accumulation -> py [j][128] ---------
// grid 256 (u), 256 threads (t). Register-accumulated over sorted b, flush at
// group boundaries into LDS numy[100][257]; then divide + write py tile.
__global__ __launch_bounds__(256) void kB(const float* __restrict__ P01,
                                          const float* __restrict__ P23,
                                          const int* __restrict__ bidx,
                                          const int* __restrict__ ylab,
                                          float* __restrict__ py) {
    __shared__ float numy[100 * 257];        // 102,800 B
    __shared__ float aA[1024];
    __shared__ int   blist[1024];
    __shared__ unsigned char yl[1024];
    __shared__ float numjl[256];
    int t = threadIdx.x;
    int u = blockIdx.x;

    for (int i = t; i < 1024; i += 256) {
        int b = bidx[i];
        blist[i] = b;
        aA[i] = P01[b * 256 + u];
        yl[i] = (unsigned char)ylab[i];
    }
    for (int i = t; i < 100 * 257; i += 256) numy[i] = 0.f;
    __syncthreads();

    float numj = 0.f;
    float acc = 0.f;
    int ycur = yl[0];

    float v[8];
    #pragma unroll
    for (int k = 0; k < 8; ++k) v[k] = P23[blist[k] * 256 + t];

    for (int c = 0; c < 128; ++c) {
        float w[8];
        if (c < 127) {
            #pragma unroll
            for (int k = 0; k < 8; ++k) w[k] = P23[blist[(c + 1) * 8 + k] * 256 + t];
        }
        #pragma unroll
        for (int k = 0; k < 8; ++k) {
            int i = c * 8 + k;
            int y = yl[i];
            if (y != ycur) {
                numy[ycur * 257 + t] = acc;
                numj += acc;
                acc = 0.f;
                ycur = y;
            }
            acc = fmaf(aA[i], v[k], acc);
        }
        if (c < 127) {
            #pragma unroll
            for (int k = 0; k < 8; ++k) v[k] = w[k];
        }
    }
    numy[ycur * 257 + t] = acc;
    numj += acc;
    numjl[t] = numj;
    __syncthreads();

    // write py[(u*256+tt)*128 + y], y 0..127 (>=100 zero), float4 coalesced
    for (int it = 0; it < 32; ++it) {
        int idx = it * 256 + t;
        int tt = idx >> 5;
        int y4 = (idx & 31) << 2;
        float rnj = 1.0f / fmaxf(numjl[tt], EPS);
        float4 o;
        float* op = &o.x;
        #pragma unroll
        for (int q = 0; q < 4; ++q) {
            int y = y4 + q;
            float val = 0.f;
            if (y < 100) val = fminf(fmaxf(numy[y * 257 + tt], EPS) * rnj, 1.0f);
            op[q] = val;
        }
        *reinterpret_cast<float4*>(py + (size_t)(u * 256 + tt) * 128 + y4) = o;
    }
}

// ---- Kernel C: probs partials — fp32 register-tiled GEMM ------------------
// grid (8 b-blocks, jsplit), 256 threads. Block tile 128b x 128y, thread 8x8.
__global__ __launch_bounds__(256) void kC(const float* __restrict__ sm,
                                          const float* __restrict__ py,
                                          float* __restrict__ part,
                                          int jper) {
    __shared__ float smb[128 * 65];
    int t = threadIdx.x;
    int bbase = blockIdx.x << 7;
    int jblk = blockIdx.y;

    for (int i = t; i < 128 * 64; i += 256) {
        smb[(i >> 6) * 65 + (i & 63)] = sm[(size_t)(bbase + (i >> 6)) * 64 + (i & 63)];
    }
    __syncthreads();

    int tb = t & 15, ty = t >> 4;
    float acc[8][8];
    #pragma unroll
    for (int k = 0; k < 8; ++k)
        #pragma unroll
        for (int yi = 0; yi < 8; ++yi) acc[k][yi] = 0.f;

    int jstart = jblk * jper;
    int nch = jper >> 4;
    for (int c = 0; c < nch; ++c) {
        int jc = jstart + (c << 4);
        int s0 = (jc >> 12) & 15, s1 = (jc >> 8) & 15, s2 = (jc >> 4) & 15;
        float pre[8];
        #pragma unroll
        for (int k = 0; k < 8; ++k) {
            int bo = (tb + (k << 4)) * 65;
            pre[k] = smb[bo + s0] * smb[bo + 16 + s1] * smb[bo + 32 + s2];
        }
        #pragma unroll 4
        for (int s3 = 0; s3 < 16; ++s3) {
            const float4* pv = reinterpret_cast<const float4*>(py + (size_t)(jc + s3) * 128);
            float4 p0 = pv[ty * 2];
            float4 p1 = pv[ty * 2 + 1];
            float g[8];
            #pragma unroll
            for (int k = 0; k < 8; ++k)
                g[k] = pre[k] * smb[(tb + (k << 4)) * 65 + 48 + s3];
            float pyv[8] = {p0.x, p0.y, p0.z, p0.w, p1.x, p1.y, p1.z, p1.w};
            #pragma unroll
            for (int k = 0; k < 8; ++k)
                #pragma unroll
                for (int yi = 0; yi < 8; ++yi)
                    acc[k][yi] = fmaf(g[k], pyv[yi], acc[k][yi]);
        }
    }

    #pragma unroll
    for (int yi = 0; yi < 8; ++yi) {
        int y = ty * 8 + yi;
        size_t base = ((size_t)jblk * 128 + y) * 1024 + bbase + tb;
        #pragma unroll
        for (int k = 0; k < 8; ++k)
            part[base + (k << 4)] = acc[k][yi];
    }
}

// ---- Kernel D: reduce j-split partials -> out[b*100+y] --------------------
__global__ __launch_bounds__(256) void kD(const float* __restrict__ part,
                                          float* __restrict__ out,
                                          int jsplit) {
    int t = threadIdx.x;
    int y = blockIdx.x >> 2;
    int b = ((blockIdx.x & 3) << 8) + t;
    float s = 0.f;
    for (int jb = 0; jb < jsplit; ++jb)
        s += part[(((size_t)jb * 128 + y) << 10) + b];
    out[(size_t)b * 100 + y] = s;
}

extern "C" void kernel_launch(void* const* d_in, const int* in_sizes, int n_in,
                              void* d_out, int out_size, void* d_ws, size_t ws_size,
                              hipStream_t stream) {
    const float* logits = (const float*)d_in[0];
    const float* y_true = (const float*)d_in[1];
    float* out = (float*)d_out;

    char* ws = (char*)d_ws;
    float* sm   = (float*)(ws);                  // 256 KB
    int*   lab  = (int*)(ws + 262144);           // 4 KB
    float* P01  = (float*)(ws + 524288);         // 1 MB
    float* P23  = (float*)(ws + 1572864);        // 1 MB
    int*   bidx = (int*)(ws + 2621440);          // 4 KB
    int*   ylab = (int*)(ws + 2625536);          // 4 KB
    float* py   = (float*)(ws + 3145728);        // 33.5 MB
    size_t part_off = 3145728 + 33554432ull;
    float* part = (float*)(ws + part_off);

    int jsplit = 128;
    while (jsplit > 1 &&
           part_off + (size_t)jsplit * 128 * 1024 * 4 > ws_size)
        jsplit >>= 1;
    int jper = 65536 / jsplit;

    kA<<<1024, 256, 0, stream>>>(logits, y_true, sm, P01, P23, lab);
    kS<<<1, 1024, 0, stream>>>(lab, bidx, ylab);
    kB<<<256, 256, 0, stream>>>(P01, P23, bidx, ylab, py);
    dim3 gC(8, jsplit);
    kC<<<gC, 256, 0, stream>>>(sm, py, part, jper);
    kD<<<400, 256, 0, stream>>>(part, out, jsplit);
}

// Round 3
// 252.503 us; speedup vs baseline: 3.1734x; 1.5615x over previous
//
#include <hip/hip_runtime.h>
#include <hip/hip_bf16.h>

#define EPS 1e-6f

typedef float f32x4 __attribute__((ext_vector_type(4)));
typedef __bf16 bf16x8 __attribute__((ext_vector_type(8)));
typedef short short8 __attribute__((ext_vector_type(8)));

static __device__ __forceinline__ short bf16bits(float x) {
    __hip_bfloat16 h = __float2bfloat16(x);
    short s;
    __builtin_memcpy(&s, &h, 2);
    return s;
}
static __device__ __forceinline__ float bf16back(float x) {
    __hip_bfloat16 h = __float2bfloat16(x);
    return __bfloat162float(h);
}

// ---- Kernel A: softmax + P01/P23 pair products (+transposed/swizzled/split)
__global__ __launch_bounds__(256) void kA(const float* __restrict__ logits,
                                          const float* __restrict__ y_true,
                                          float* __restrict__ P01,
                                          float* __restrict__ P23,
                                          float* __restrict__ P01T,
                                          short* __restrict__ P23s_hi,
                                          short* __restrict__ P23s_lo,
                                          int* __restrict__ label) {
    __shared__ float row[64];
    int b = blockIdx.x, t = threadIdx.x;
    if (t < 64) {
        float x = logits[b * 64 + t];
        float m = x;
        for (int mk = 8; mk >= 1; mk >>= 1) m = fmaxf(m, __shfl_xor(m, mk, 16));
        float e = __expf(x - m);
        float s = e;
        for (int mk = 8; mk >= 1; mk >>= 1) s += __shfl_xor(s, mk, 16);
        row[t] = e / s;
    }
    if (t >= 128 && t < 228) {
        int y = t - 128;
        if (y_true[b * 100 + y] > 0.5f) label[b] = y;
    }
    __syncthreads();
    int hi = t >> 4, lo = t & 15;
    float v01 = row[hi] * row[16 + lo];
    float v23 = row[32 + hi] * row[48 + lo];
    P01[b * 256 + t] = v01;
    P01T[t * 1024 + b] = v01;
    P23[b * 256 + t] = v23;
    float hf = bf16back(v23);
    int ts = t ^ ((b & 7) << 3);   // XOR swizzle (matches kC LDS read)
    P23s_hi[b * 256 + ts] = bf16bits(v23);
    P23s_lo[b * 256 + ts] = bf16bits(v23 - hf);
}

// ---- Kernel S: deterministic counting sort of b by label -------------------
__global__ __launch_bounds__(1024) void kS(const int* __restrict__ label,
                                           int* __restrict__ bidx,
                                           int* __restrict__ ylab) {
    __shared__ int lab[1024];
    __shared__ int offs[101];
    int t = threadIdx.x;
    lab[t] = label[t];
    __syncthreads();
    if (t <= 100) {
        int c = 0;
        for (int b = 0; b < 1024; ++b) c += (lab[b] < t) ? 1 : 0;
        offs[t] = c;
    }
    __syncthreads();
    int my = lab[t];
    int rank = 0;
    for (int b = 0; b < t; ++b) rank += (lab[b] == my) ? 1 : 0;
    int pos = offs[my] + rank;
    bidx[pos] = t;
    ylab[pos] = my;
}

// ---- Kernel B: segmented accumulation -> pyT_hi/lo [y][65536] bf16 ---------
// 512 threads: 2 b-groups of 512 sorted rows each; LDS atomic merge (2
// contributors -> bitwise deterministic).
__global__ __launch_bounds__(512) void kB(const float* __restrict__ P01,
                                          const float* __restrict__ P23,
                                          const int* __restrict__ bidx,
                                          const int* __restrict__ ylab,
                                          short* __restrict__ pyT_hi,
                                          short* __restrict__ pyT_lo) {
    __shared__ float numy[100 * 257];
    __shared__ float aA[1024];
    __shared__ int blist[1024];
    __shared__ unsigned char yl[1024];
    __shared__ float numjl[2][256];
    int t = threadIdx.x;
    int u = blockIdx.x;

    for (int i = t; i < 1024; i += 512) {
        int b = bidx[i];
        blist[i] = b;
        aA[i] = P01[b * 256 + u];
        yl[i] = (unsigned char)ylab[i];
    }
    for (int i = t; i < 100 * 257; i += 512) numy[i] = 0.f;
    __syncthreads();

    int g = t >> 8;       // group 0/1
    int tc = t & 255;     // t-column
    int i0 = g << 9;

    float numj = 0.f, acc = 0.f;
    int ycur = yl[i0];
    float v[8];
    #pragma unroll
    for (int k = 0; k < 8; ++k) v[k] = P23[blist[i0 + k] * 256 + tc];

    for (int c = 0; c < 64; ++c) {
        float w[8];
        if (c < 63) {
            #pragma unroll
            for (int k = 0; k < 8; ++k) w[k] = P23[blist[i0 + (c + 1) * 8 + k] * 256 + tc];
        }
        #pragma unroll
        for (int k = 0; k < 8; ++k) {
            int i = i0 + c * 8 + k;
            int y = yl[i];
            if (y != ycur) {
                atomicAdd(&numy[ycur * 257 + tc], acc);
                numj += acc;
                acc = 0.f;
                ycur = y;
            }
            acc = fmaf(aA[i], v[k], acc);
        }
        if (c < 63) {
            #pragma unroll
            for (int k = 0; k < 8; ++k) v[k] = w[k];
        }
    }
    atomicAdd(&numy[ycur * 257 + tc], acc);
    numj += acc;
    numjl[g][tc] = numj;
    __syncthreads();

    // write pyT hi/lo: [y][u*256 + t], packed 2 t's per u32 store
    for (int it = 0; it < 32; ++it) {
        int idx = it * 512 + t;       // 0..16383
        int y = idx >> 7;             // 0..127
        int t0 = (idx & 127) << 1;
        float v0 = 0.f, v1 = 0.f;
        if (y < 100) {
            float nj0 = fmaxf(numjl[0][t0] + numjl[1][t0], EPS);
            float nj1 = fmaxf(numjl[0][t0 + 1] + numjl[1][t0 + 1], EPS);
            v0 = fminf(fmaxf(numy[y * 257 + t0], EPS) / nj0, 1.0f);
            v1 = fminf(fmaxf(numy[y * 257 + t0 + 1], EPS) / nj1, 1.0f);
        }
        unsigned h0 = (unsigned short)bf16bits(v0);
        unsigned h1 = (unsigned short)bf16bits(v1);
        unsigned l0 = (unsigned short)bf16bits(v0 - bf16back(v0));
        unsigned l1 = (unsigned short)bf16bits(v1 - bf16back(v1));
        size_t ei = ((size_t)y * 65536 + (size_t)u * 256 + t0) >> 1;
        ((unsigned*)pyT_hi)[ei] = h0 | (h1 << 16);
        ((unsigned*)pyT_lo)[ei] = l0 | (l1 << 16);
    }
}

// ---- Kernel C: MFMA GEMM.  part[uspl][y][b] = sum_{u in slice} P01[b,u]*Q_u
// block: 128b x 128y x 8u; 512 thr = 8 waves (4 b-groups x 2 y-groups).
// A (P23 hi/lo bf16, swizzled) staged once in LDS; B (pyT hi/lo) streamed.
__global__ __launch_bounds__(512, 2) void kC(const short* __restrict__ P23s_hi,
                                             const short* __restrict__ P23s_lo,
                                             const float* __restrict__ P01T,
                                             const short* __restrict__ pyT_hi,
                                             const short* __restrict__ pyT_lo,
                                             float* __restrict__ part) {
    __shared__ short Ahi[128 * 256];
    __shared__ short Alo[128 * 256];
    __shared__ float p01s[8 * 128];
    int t = threadIdx.x;
    int bb = blockIdx.x >> 5, uspl = blockIdx.x & 31;
    int bbase = bb << 7;
    int u0 = uspl << 3;

    #pragma unroll
    for (int r = 0; r < 8; ++r) {
        int c = r * 512 + t;   // short8 chunk 0..4095
        *(short8*)(Ahi + c * 8) = *(const short8*)(P23s_hi + bbase * 256 + c * 8);
        *(short8*)(Alo + c * 8) = *(const short8*)(P23s_lo + bbase * 256 + c * 8);
    }
    for (int i = t; i < 1024; i += 512)
        p01s[i] = P01T[(u0 + (i >> 7)) * 1024 + bbase + (i & 127)];
    __syncthreads();

    int lane = t & 63;
    int wave = t >> 6;
    int wb = wave >> 1, wy = wave & 1;
    int l15 = lane & 15, l4 = lane >> 4;
    int hi8 = l4 << 3;

    int rowA0 = wb * 32 + l15;
    int swz = (rowA0 & 7) << 3;            // same for rowA0+16
    const short* pA0h = Ahi + rowA0 * 256;
    const short* pA0l = Alo + rowA0 * 256;
    const short* pA1h = pA0h + 16 * 256;
    const short* pA1l = pA0l + 16 * 256;

    const short* bh[4];
    const short* bl[4];
    #pragma unroll
    for (int n = 0; n < 4; ++n) {
        int y = wy * 64 + n * 16 + l15;
        bh[n] = pyT_hi + (size_t)y * 65536 + hi8;
        bl[n] = pyT_lo + (size_t)y * 65536 + hi8;
    }

    const f32x4 zero4 = {0.f, 0.f, 0.f, 0.f};
    f32x4 P[2][4];
    #pragma unroll
    for (int m = 0; m < 2; ++m)
        #pragma unroll
        for (int n = 0; n < 4; ++n) P[m][n] = zero4;

    bf16x8 BhA[4], BlA[4], BhB[4], BlB[4];
    {
        int off = u0 * 256;
        #pragma unroll
        for (int n = 0; n < 4; ++n) {
            BhA[n] = *(const bf16x8*)(bh[n] + off);
            BlA[n] = *(const bf16x8*)(bl[n] + off);
        }
    }

#define KSTEP(CURH, CURL, NXTH, NXTL, PRE, NOFF)                                          \
    {                                                                                     \
        int aoff = (ks * 32 + hi8) ^ swz;                                                 \
        bf16x8 a0h = *(const bf16x8*)(pA0h + aoff);                                       \
        bf16x8 a0l = *(const bf16x8*)(pA0l + aoff);                                       \
        bf16x8 a1h = *(const bf16x8*)(pA1h + aoff);                                       \
        bf16x8 a1l = *(const bf16x8*)(pA1l + aoff);                                       \
        if (PRE) {                                                                        \
            int noff_ = (NOFF);                                                           \
            _Pragma("unroll")                                                             \
            for (int n = 0; n < 4; ++n) {                                                 \
                NXTH[n] = *(const bf16x8*)(bh[n] + noff_);                                \
                NXTL[n] = *(const bf16x8*)(bl[n] + noff_);                                \
            }                                                                             \
        }                                                                                 \
        _Pragma("unroll")                                                                 \
        for (int n = 0; n < 4; ++n) {                                                     \
            if (ks == 0) {                                                                \
                Q[0][n] = __builtin_amdgcn_mfma_f32_16x16x32_bf16(a0h, CURH[n], zero4, 0, 0, 0); \
                Q[1][n] = __builtin_amdgcn_mfma_f32_16x16x32_bf16(a1h, CURH[n], zero4, 0, 0, 0); \
            } else {                                                                      \
                Q[0][n] = __builtin_amdgcn_mfma_f32_16x16x32_bf16(a0h, CURH[n], Q[0][n], 0, 0, 0); \
                Q[1][n] = __builtin_amdgcn_mfma_f32_16x16x32_bf16(a1h, CURH[n], Q[1][n], 0, 0, 0); \
            }                                                                             \
            Q[0][n] = __builtin_amdgcn_mfma_f32_16x16x32_bf16(a0h, CURL[n], Q[0][n], 0, 0, 0); \
            Q[1][n] = __builtin_amdgcn_mfma_f32_16x16x32_bf16(a1h, CURL[n], Q[1][n], 0, 0, 0); \
            Q[0][n] = __builtin_amdgcn_mfma_f32_16x16x32_bf16(a0l, CURH[n], Q[0][n], 0, 0, 0); \
            Q[1][n] = __builtin_amdgcn_mfma_f32_16x16x32_bf16(a1l, CURH[n], Q[1][n], 0, 0, 0); \
        }                                                                                 \
    }

    for (int uu = 0; uu < 8; ++uu) {
        int ub = (u0 + uu) * 256;
        f32x4 Q[2][4];
        #pragma unroll
        for (int ks = 0; ks < 8; ++ks) {
            if ((ks & 1) == 0) {
                KSTEP(BhA, BlA, BhB, BlB, true, ub + (ks + 1) * 32)
            } else {
                bool pre = !(uu == 7 && ks == 7);
                KSTEP(BhB, BlB, BhA, BlA, pre, (ks == 7) ? (ub + 256) : (ub + (ks + 1) * 32))
            }
        }
        #pragma unroll
        for (int m = 0; m < 2; ++m) {
            f32x4 pv = *(const f32x4*)(p01s + uu * 128 + wb * 32 + m * 16 + (l4 << 2));
            #pragma unroll
            for (int n = 0; n < 4; ++n) P[m][n] += pv * Q[m][n];
        }
    }
#undef KSTEP

    size_t pbase = (size_t)uspl * 128 * 1024;
    #pragma unroll
    for (int m = 0; m < 2; ++m)
        #pragma unroll
        for (int n = 0; n < 4; ++n) {
            int y = wy * 64 + n * 16 + l15;
            int bg = bbase + wb * 32 + m * 16 + (l4 << 2);
            *(f32x4*)(part + pbase + (size_t)y * 1024 + bg) = P[m][n];
        }
}

// ---- Kernel D: reduce 32 u-split partials -> out[b*100+y] ------------------
__global__ __launch_bounds__(256) void kD(const float* __restrict__ part,
                                          float* __restrict__ out) {
    int t = threadIdx.x;
    int y = blockIdx.x >> 2;
    int b = ((blockIdx.x & 3) << 8) + t;
    float s = 0.f;
    for (int q = 0; q < 32; ++q)
        s += part[(((size_t)q * 128 + y) << 10) + b];
    out[(size_t)b * 100 + y] = s;
}

extern "C" void kernel_launch(void* const* d_in, const int* in_sizes, int n_in,
                              void* d_out, int out_size, void* d_ws, size_t ws_size,
                              hipStream_t stream) {
    const float* logits = (const float*)d_in[0];
    const float* y_true = (const float*)d_in[1];
    float* out = (float*)d_out;

    char* ws = (char*)d_ws;
    float* P01    = (float*)(ws);                        // 1 MB
    float* P23    = (float*)(ws + (1u << 20));           // 1 MB
    float* P01T   = (float*)(ws + (2u << 20));           // 1 MB
    short* P23s_hi = (short*)(ws + (3u << 20));          // 512 KB
    short* P23s_lo = (short*)(ws + (3u << 20) + (512u << 10)); // 512 KB
    int*   lab    = (int*)(ws + (4u << 20));             // 4 KB
    int*   bidx   = (int*)(ws + (4u << 20) + 4096);
    int*   ylab   = (int*)(ws + (4u << 20) + 8192);
    short* pyT_hi = (short*)(ws + (8u << 20));           // 16 MB
    short* pyT_lo = (short*)(ws + (24u << 20));          // 16 MB
    float* part   = (float*)(ws + (40u << 20));          // 16 MB

    kA<<<1024, 256, 0, stream>>>(logits, y_true, P01, P23, P01T, P23s_hi, P23s_lo, lab);
    kS<<<1, 1024, 0, stream>>>(lab, bidx, ylab);
    kB<<<256, 512, 0, stream>>>(P01, P23, bidx, ylab, pyT_hi, pyT_lo);
    kC<<<256, 512, 0, stream>>>(P23s_hi, P23s_lo, P01T, pyT_hi, pyT_lo, part);
    kD<<<400, 256, 0, stream>>>(part, out);
}